// Round 11
// baseline (172.183 us; speedup 1.0000x reference)
//
#include <hip/hip_runtime.h>

typedef short short8 __attribute__((ext_vector_type(8)));
typedef float f32x4 __attribute__((ext_vector_type(4)));
typedef float f32x16 __attribute__((ext_vector_type(16)));

#define SQ   1024
#define DIN  768
#define NH   12
#define DH   64
#define SCL2 0.1803368801111243f   /* 0.125 * log2(e) */

static __device__ __forceinline__ ushort f2bf(float f) {
  union { float f; unsigned u; } v; v.f = f;
  unsigned u = v.u;
  unsigned r = (u + 0x7FFFu + ((u >> 16) & 1u)) >> 16;
  return (ushort)r;
}
// hardware packed f32->bf16 (RNE); dst.lo=a, dst.hi=b
static __device__ __forceinline__ unsigned cvtpk(float a, float b) {
  unsigned r;
  asm("v_cvt_pk_bf16_f32 %0, %1, %2" : "=v"(r) : "v"(a), "v"(b));
  return r;
}

static __device__ __forceinline__ void gload_lds16(const ushort* g, ushort* l) {
  __builtin_amdgcn_global_load_lds(
      (const __attribute__((address_space(1))) unsigned*)(g),
      (__attribute__((address_space(3))) unsigned*)(l),
      16, 0, 0);
}

// ---------------------------------------------------------------- prep: x -> bf16
__global__ __launch_bounds__(256) void k_convert_x(const float* __restrict__ x,
                                                   ushort* __restrict__ xb) {
  int i = (blockIdx.x * 256 + threadIdx.x) * 8;
  float4 v0 = *reinterpret_cast<const float4*>(x + i);
  float4 v1 = *reinterpret_cast<const float4*>(x + i + 4);
  uint4 o;
  o.x = cvtpk(v0.x, v0.y); o.y = cvtpk(v0.z, v0.w);
  o.z = cvtpk(v1.x, v1.y); o.w = cvtpk(v1.z, v1.w);
  *reinterpret_cast<uint4*>(xb + i) = o;
}

// ------------------------------- prep: W[h][d][e] -> Wt[(m*12+h)*64+e][d] bf16 (B^T)
__global__ __launch_bounds__(256) void k_prep_w(const float* __restrict__ Wq,
                                                const float* __restrict__ Wk,
                                                const float* __restrict__ Wv,
                                                ushort* __restrict__ wt) {
  __shared__ ushort tile[64][65];
  const int mh = blockIdx.x;            // m*12 + h
  const int m = mh / 12, h = mh % 12;
  const int d0 = blockIdx.y * 64;
  const float* W = (m == 0 ? Wq : (m == 1 ? Wk : Wv)) + h * DIN * DH;
  ushort* outp = wt + (size_t)mh * DH * DIN;
  #pragma unroll
  for (int p = 0; p < 16; ++p) {
    int idx = p * 256 + threadIdx.x;
    int d = idx >> 6, e = idx & 63;
    tile[d][e] = f2bf(W[(d0 + d) * DH + e]);
  }
  __syncthreads();
  #pragma unroll
  for (int p = 0; p < 16; ++p) {
    int idx = p * 256 + threadIdx.x;
    int e = idx >> 6, d = idx & 63;
    outp[e * DIN + d0 + d] = tile[d][e];
  }
}

// ------------------------------------------------- QKV projection as ONE GEMM
// (unchanged from R10: 128x128, BK=32, mfma_32x32x16, 3-buf depth-2 counted vmcnt)
__global__ __launch_bounds__(256) void k_proj(const ushort* __restrict__ xb,
                                              const ushort* __restrict__ wt,
                                              ushort* __restrict__ qo,
                                              ushort* __restrict__ ko,
                                              ushort* __restrict__ vto) {
  __shared__ __align__(16) ushort Sb[24576];   // 48 KB: A 3x8KB @0, B 3x8KB @12288

  const int brow = blockIdx.x * 128;
  const int bn   = blockIdx.y * 128;
  const int w    = threadIdx.x >> 6, lane = threadIdx.x & 63;
  const int ql   = lane & 31, hi = lane >> 5;
  const int wm   = w >> 1, wn = w & 1;

  const int srow  = threadIdx.x >> 2;                          // 0..63
  const int sslot = (threadIdx.x & 3) ^ (srow & 3) ^ ((srow >> 2) & 3);
  const ushort* gA = xb + (size_t)(brow + srow) * DIN + sslot * 8;
  const ushort* gB = wt + (size_t)(bn   + srow) * DIN + sslot * 8;

  f32x16 acc[2][2];
  #pragma unroll
  for (int i = 0; i < 2; ++i)
    #pragma unroll
    for (int j = 0; j < 2; ++j)
      #pragma unroll
      for (int r = 0; r < 16; ++r) acc[i][j][r] = 0.f;

  const int frq = (ql & 3) ^ ((ql >> 2) & 3);     // f(row) depends on ql only

#define STAGEP(bi, tt) do {                                               \
    const int k0_ = (tt) * 32;                                            \
    ushort* la_ = Sb + (bi) * 4096 + threadIdx.x * 8;                     \
    ushort* lb_ = Sb + 12288 + (bi) * 4096 + threadIdx.x * 8;             \
    gload_lds16(gA + k0_,            la_);                                \
    gload_lds16(gA + k0_ + 64 * DIN, la_ + 2048);                         \
    gload_lds16(gB + k0_,            lb_);                                \
    gload_lds16(gB + k0_ + 64 * DIN, lb_ + 2048);                         \
  } while (0)

  STAGEP(0, 0);
  STAGEP(1, 1);

  int cur = 0;
  #pragma unroll 1
  for (int t = 0; t < 24; ++t) {
    if (t < 23) asm volatile("s_waitcnt vmcnt(4)" ::: "memory");
    else        asm volatile("s_waitcnt vmcnt(0)" ::: "memory");
    __builtin_amdgcn_sched_barrier(0);
    __builtin_amdgcn_s_barrier();
    __builtin_amdgcn_sched_barrier(0);
    if (t + 2 < 24) {
      int nb = cur + 2; if (nb >= 3) nb -= 3;
      STAGEP(nb, t + 2);
    }
    short8 a[2][2], b[2][2];
    #pragma unroll
    for (int ai = 0; ai < 2; ++ai) {
      const int row = wm * 64 + ai * 32 + ql;
      #pragma unroll
      for (int ks = 0; ks < 2; ++ks)
        a[ai][ks] = *reinterpret_cast<const short8*>(
            &Sb[cur * 4096 + row * 32 + (((ks * 2 + hi) ^ frq) * 8)]);
    }
    #pragma unroll
    for (int ci = 0; ci < 2; ++ci) {
      const int row = wn * 64 + ci * 32 + ql;
      #pragma unroll
      for (int ks = 0; ks < 2; ++ks)
        b[ci][ks] = *reinterpret_cast<const short8*>(
            &Sb[12288 + cur * 4096 + row * 32 + (((ks * 2 + hi) ^ frq) * 8)]);
    }
    #pragma unroll
    for (int ai = 0; ai < 2; ++ai)
      #pragma unroll
      for (int ci = 0; ci < 2; ++ci) {
        acc[ai][ci] = __builtin_amdgcn_mfma_f32_32x32x16_bf16(a[ai][0], b[ci][0], acc[ai][ci], 0, 0, 0);
        acc[ai][ci] = __builtin_amdgcn_mfma_f32_32x32x16_bf16(a[ai][1], b[ci][1], acc[ai][ci], 0, 0, 0);
      }
    cur += 1; if (cur >= 3) cur = 0;
  }
#undef STAGEP

  __syncthreads();   // scratch below overlaps live buffers of the last iteration

  ushort* ldsw = Sb + w * 4096;                  // wave-private 64x64 ushort tile
  const int mh = blockIdx.y * 2 + wn;
  const int m = mh / 12, h = mh % 12;
  const int c = lane & 7;

  if (m < 2) {
    #pragma unroll
    for (int ai = 0; ai < 2; ++ai)
      #pragma unroll
      for (int ci = 0; ci < 2; ++ci)
        #pragma unroll
        for (int r = 0; r < 16; ++r) {
          int sl = ai * 32 + (r & 3) + 8 * (r >> 2) + 4 * hi;
          int e  = ci * 32 + ql;
          ldsw[sl * 64 + (e ^ ((sl & 7) << 3))] = f2bf(acc[ai][ci][r]);
        }
    asm volatile("s_waitcnt lgkmcnt(0)" ::: "memory");
    ushort* dst = (m == 0) ? qo : ko;
    #pragma unroll
    for (int it = 0; it < 8; ++it) {
      int sl = it * 8 + (lane >> 3);
      short8 vv = *reinterpret_cast<const short8*>(&ldsw[sl * 64 + ((c * 8) ^ ((sl & 7) << 3))]);
      int rg = brow + wm * 64 + sl;
      int b_ = rg >> 10, s_ = rg & 1023;
      *reinterpret_cast<short8*>(dst + ((size_t)(b_ * 12 + h) * SQ + s_) * DH + c * 8) = vv;
    }
  } else {
    #pragma unroll
    for (int ai = 0; ai < 2; ++ai)
      #pragma unroll
      for (int ci = 0; ci < 2; ++ci)
        #pragma unroll
        for (int r = 0; r < 16; ++r) {
          int sl = ai * 32 + (r & 3) + 8 * (r >> 2) + 4 * hi;
          int e  = ci * 32 + ql;
          ldsw[e * 64 + (sl ^ ((e & 7) << 3))] = f2bf(acc[ai][ci][r]);
        }
    asm volatile("s_waitcnt lgkmcnt(0)" ::: "memory");
    #pragma unroll
    for (int it = 0; it < 8; ++it) {
      int e = it * 8 + (lane >> 3);
      short8 vv = *reinterpret_cast<const short8*>(&ldsw[e * 64 + ((c * 8) ^ ((e & 7) << 3))]);
      int rg = brow + wm * 64 + c * 8;
      int b_ = rg >> 10, s_ = rg & 1023;
      *reinterpret_cast<short8*>(vto + ((size_t)(b_ * 12 + h) * DH + e) * SQ + s_) = vv;
    }
  }
}

// ------------------------------------------------- fused causal flash attention
// R11 change: TREE reductions for row max & sum (the previous sequential folds were
// 31-deep dependent chains ~250 stall-cyc/tile; trees are depth-5 ~20 cyc).
__global__ __launch_bounds__(256, 3) void k_attn(const ushort* __restrict__ qi,
                                                 const ushort* __restrict__ ki,
                                                 const ushort* __restrict__ vti,
                                                 float* __restrict__ out) {
  __shared__ __align__(16) ushort Kb[2][64 * 64];
  __shared__ __align__(16) ushort Vb[2][64 * 64];

  const int f = blockIdx.x;
  const int g = f >> 8, r_ = f & 255;
  const int qt = ((r_ & 7) + g * 3) & 7;        // bijective, breaks 256-stride alignment
  const int bh = g * 32 + (r_ >> 3);
  const int b = bh / 12, h = bh % 12;
  const int w = threadIdx.x >> 6, lane = threadIdx.x & 63;
  const int ql = lane & 31, hi = lane >> 5;
  const int q0 = qt * 128 + w * 32;
  const int nt = (q0 >> 6) + 1;                 // this wave's kv-tile count
  const int ntmax = 2 * qt + 2;                 // block's kv-tile count
  const ushort* qb = qi  + (size_t)bh * SQ * DH;
  const ushort* kb = ki  + (size_t)bh * SQ * DH;
  const ushort* vb = vti + (size_t)bh * DH * SQ;

  short8 qf[4];
  #pragma unroll
  for (int m = 0; m < 4; ++m)
    qf[m] = *reinterpret_cast<const short8*>(qb + (size_t)(q0 + ql) * DH + m * 16 + hi * 8);

  f32x16 o0, o1;
  #pragma unroll
  for (int r = 0; r < 16; ++r) { o0[r] = 0.f; o1[r] = 0.f; }
  float m_run = -1e30f, l_run = 0.f;

#define STAGE(bufi, tt) do {                                                                   \
    const int kv0_ = (tt) * 64;                                                                \
    const int t0 = threadIdx.x, t1 = threadIdx.x + 256;                                        \
    gload_lds16(kb + (size_t)(kv0_ + (t0 >> 3)) * DH + (((t0 & 7) ^ ((t0 >> 3) & 7)) * 8),     \
                &Kb[bufi][0] + t0 * 8);                                                        \
    gload_lds16(kb + (size_t)(kv0_ + (t1 >> 3)) * DH + (((t1 & 7) ^ ((t1 >> 3) & 7)) * 8),     \
                &Kb[bufi][0] + t1 * 8);                                                        \
    gload_lds16(vb + (size_t)(t0 >> 3) * SQ + kv0_ + (((t0 & 7) ^ ((t0 >> 3) & 7)) * 8),       \
                &Vb[bufi][0] + t0 * 8);                                                        \
    gload_lds16(vb + (size_t)(t1 >> 3) * SQ + kv0_ + (((t1 & 7) ^ ((t1 >> 3) & 7)) * 8),       \
                &Vb[bufi][0] + t1 * 8);                                                        \
  } while (0)

  STAGE(0, 0);
  __syncthreads();

  int cur = 0;
  #pragma unroll 1
  for (int t = 0; t < ntmax; ++t) {
    if (t + 1 < ntmax) STAGE(cur ^ 1, t + 1);

    if (t < nt) {
      const int kv0 = t * 64;
      const ushort* Kc = &Kb[cur][0];
      const ushort* Vc = &Vb[cur][0];

      f32x16 s0, s1;
      #pragma unroll
      for (int r = 0; r < 16; ++r) { s0[r] = 0.f; s1[r] = 0.f; }
      #pragma unroll
      for (int m = 0; m < 4; ++m) {
        short8 kf = *reinterpret_cast<const short8*>(Kc + ql * 64 + ((2 * m + hi) ^ (ql & 7)) * 8);
        s0 = __builtin_amdgcn_mfma_f32_32x32x16_bf16(kf, qf[m], s0, 0, 0, 0);
      }
      #pragma unroll
      for (int m = 0; m < 4; ++m) {
        short8 kf = *reinterpret_cast<const short8*>(Kc + (32 + ql) * 64 + ((2 * m + hi) ^ (ql & 7)) * 8);
        s1 = __builtin_amdgcn_mfma_f32_32x32x16_bf16(kf, qf[m], s1, 0, 0, 0);
      }

      if (t == nt - 1) {
        const int qg = q0 + ql;
        #pragma unroll
        for (int r = 0; r < 16; ++r) {
          int kvl = (r & 3) + 8 * (r >> 2) + 4 * hi;
          if (kv0 + kvl      > qg) s0[r] = -1e30f;
          if (kv0 + 32 + kvl > qg) s1[r] = -1e30f;
        }
      }

      // ---- row max: depth-5 tree (16 pair-merges, then 4 levels)
      float tr[16];
      #pragma unroll
      for (int r = 0; r < 16; ++r) tr[r] = fmaxf(s0[r], s1[r]);
      #pragma unroll
      for (int off = 8; off >= 1; off >>= 1)
        #pragma unroll
        for (int i = 0; i < 8; ++i)
          if (i < off) tr[i] = fmaxf(tr[i], tr[i + off]);
      float mt = fmaxf(tr[0], __shfl_xor(tr[0], 32));

      if (__any(mt > m_run + 40.0f)) {
        float mnew = fmaxf(m_run, mt);
        float corr = exp2f((m_run - mnew) * SCL2);
        l_run *= corr; m_run = mnew;
        #pragma unroll
        for (int r = 0; r < 16; ++r) {
          float cr = __shfl(corr, (r & 3) + 8 * (r >> 2) + 4 * hi);
          o0[r] *= cr; o1[r] *= cr;
        }
      }
      // ---- exp (independent) + sum tree (depth-5)
      #pragma unroll
      for (int r = 0; r < 16; ++r) {
        s0[r] = exp2f((s0[r] - m_run) * SCL2);
        s1[r] = exp2f((s1[r] - m_run) * SCL2);
      }
      #pragma unroll
      for (int r = 0; r < 16; ++r) tr[r] = s0[r] + s1[r];
      #pragma unroll
      for (int off = 8; off >= 1; off >>= 1)
        #pragma unroll
        for (int i = 0; i < 8; ++i)
          if (i < off) tr[i] = tr[i] + tr[i + off];
      l_run += tr[0] + __shfl_xor(tr[0], 32);

#define PV_CHUNK(SV, CC, KC) do {                                                              \
        unsigned wa = cvtpk(SV[(CC) * 8 + 0], SV[(CC) * 8 + 1]);                               \
        unsigned wb = cvtpk(SV[(CC) * 8 + 2], SV[(CC) * 8 + 3]);                               \
        unsigned wc = cvtpk(SV[(CC) * 8 + 4], SV[(CC) * 8 + 5]);                               \
        unsigned wd = cvtpk(SV[(CC) * 8 + 6], SV[(CC) * 8 + 7]);                               \
        unsigned xa = __shfl_xor(wa, 32), xb2 = __shfl_xor(wb, 32);                            \
        unsigned xc = __shfl_xor(wc, 32), xd = __shfl_xor(wd, 32);                             \
        uint4 pw;                                                                              \
        pw.x = hi ? xc : wa;  pw.y = hi ? xd : wb;                                             \
        pw.z = hi ? wc : xa;  pw.w = hi ? wd : xb2;                                            \
        short8 pa = *reinterpret_cast<short8*>(&pw);                                           \
        short8 vf0 = *reinterpret_cast<const short8*>(Vc + ql * 64 +                           \
                       ((2 * (KC) + hi) ^ (ql & 7)) * 8);                                      \
        o0 = __builtin_amdgcn_mfma_f32_32x32x16_bf16(pa, vf0, o0, 0, 0, 0);                    \
        short8 vf1 = *reinterpret_cast<const short8*>(Vc + (32 + ql) * 64 +                    \
                       ((2 * (KC) + hi) ^ (ql & 7)) * 8);                                      \
        o1 = __builtin_amdgcn_mfma_f32_32x32x16_bf16(pa, vf1, o1, 0, 0, 0);                    \
      } while (0)

      PV_CHUNK(s0, 0, 0);
      PV_CHUNK(s0, 1, 1);
      PV_CHUNK(s1, 0, 2);
      PV_CHUNK(s1, 1, 3);
#undef PV_CHUNK
    }

    __syncthreads();
    cur ^= 1;
  }
#undef STAGE

  float rl = 1.0f / l_run;
  #pragma unroll
  for (int r = 0; r < 16; ++r) {
    int base = (r & 3) + 8 * (r >> 2) + 4 * hi;
    float sc_ = __shfl(rl, base);
    int qg = q0 + base;
    float* op = out + ((size_t)b * SQ + qg) * (NH * DH) + h * DH;
    op[ql]      = o0[r] * sc_;
    op[32 + ql] = o1[r] * sc_;
  }
}

extern "C" void kernel_launch(void* const* d_in, const int* in_sizes, int n_in,
                              void* d_out, int out_size, void* d_ws, size_t ws_size,
                              hipStream_t stream) {
  const float* x  = (const float*)d_in[0];
  const float* Wq = (const float*)d_in[1];
  const float* Wk = (const float*)d_in[2];
  const float* Wv = (const float*)d_in[3];
  float* out = (float*)d_out;

  char* ws = (char*)d_ws;
  ushort* xb = (ushort*)(ws);
  ushort* wt = (ushort*)(ws + 12582912);
  ushort* q  = (ushort*)(ws + 16121856);
  ushort* k  = (ushort*)(ws + 28704768);
  ushort* vt = (ushort*)(ws + 41287680);

  k_convert_x<<<3072, 256, 0, stream>>>(x, xb);
  k_prep_w<<<dim3(36, 12), 256, 0, stream>>>(Wq, Wk, Wv, wt);
  k_proj<<<dim3(64, 18), 256, 0, stream>>>(xb, wt, q, k, vt);
  k_attn<<<768, 256, 0, stream>>>(q, k, vt, out);
}